// Round 1
// baseline (1060.334 us; speedup 1.0000x reference)
//
#include <hip/hip_runtime.h>
#include <hip/hip_fp16.h>

#define HH 128
#define WW 128
#define NPIX (HH*WW)
#define NB 8
#define CIN 192
#define NHEADS 6
#define HD 32
#define SCALE 0.17677669529663687f

typedef _Float16 h2 __attribute__((ext_vector_type(2)));
typedef float f4 __attribute__((ext_vector_type(4)));

union V64B { f4 f[4]; h2 h[16]; _Float16 s[32]; };

// ---------------- projection: out = A @ W + b, A = [pixels x 192] view of [B,192,H,W] ----------------
// grid: (2048, 1, 3)  z=0 -> q (from x, scaled), z=1 -> k, z=2 -> v (from context)
// block 256: tile 64 pixels x 192 couts, each thread 4 pix x 12 couts
__global__ __launch_bounds__(256) void proj_kernel(
    const float* __restrict__ x, const float* __restrict__ ctx,
    const float* __restrict__ Wq, const float* __restrict__ bq,
    const float* __restrict__ Wk, const float* __restrict__ bk,
    const float* __restrict__ Wv, const float* __restrict__ bv,
    _Float16* __restrict__ qh, _Float16* __restrict__ kh, _Float16* __restrict__ vh)
{
    int z = blockIdx.z;
    const float* A; const float* Wt; const float* bias; _Float16* outp; float scale;
    if (z == 0)      { A = x;   Wt = Wq; bias = bq; outp = qh; scale = SCALE; }
    else if (z == 1) { A = ctx; Wt = Wk; bias = bk; outp = kh; scale = 1.f; }
    else             { A = ctx; Wt = Wv; bias = bv; outp = vh; scale = 1.f; }

    int m0 = blockIdx.x * 64;
    int b  = m0 / NPIX;
    int p0 = m0 % NPIX;
    const float* Ab = A + (size_t)b * CIN * NPIX + p0;

    __shared__ float As[16][64];
    __shared__ float Ws[16][192];

    int t = threadIdx.x;
    int pixg = (t & 15) * 4;
    int cog  = (t >> 4) * 12;

    float acc[4][12] = {};

    for (int k0 = 0; k0 < 192; k0 += 16) {
        #pragma unroll
        for (int i = 0; i < 4; i++) {
            int e = t + i * 256;
            int ci = e >> 6, pp = e & 63;
            As[ci][pp] = Ab[(size_t)(k0 + ci) * NPIX + pp];
        }
        #pragma unroll
        for (int i = 0; i < 12; i++) {
            int e = t + i * 256;
            int ci = e / 192, co = e - ci * 192;
            Ws[ci][co] = Wt[(size_t)(k0 + ci) * 192 + co];
        }
        __syncthreads();
        #pragma unroll
        for (int kk = 0; kk < 16; kk++) {
            f4 a = *(const f4*)&As[kk][pixg];
            const f4* wrow = (const f4*)&Ws[kk][cog];
            f4 w0 = wrow[0], w1 = wrow[1], w2 = wrow[2];
            #pragma unroll
            for (int i = 0; i < 4; i++) {
                float av = a[i];
                acc[i][0] += av * w0[0]; acc[i][1] += av * w0[1];
                acc[i][2] += av * w0[2]; acc[i][3] += av * w0[3];
                acc[i][4] += av * w1[0]; acc[i][5] += av * w1[1];
                acc[i][6] += av * w1[2]; acc[i][7] += av * w1[3];
                acc[i][8] += av * w2[0]; acc[i][9] += av * w2[1];
                acc[i][10] += av * w2[2]; acc[i][11] += av * w2[3];
            }
        }
        __syncthreads();
    }

    #pragma unroll
    for (int j = 0; j < 12; j++) {
        int co = cog + j;
        int g = co >> 5, d = co & 31;
        float bb = bias[co];
        #pragma unroll
        for (int i = 0; i < 4; i++) {
            int p = p0 + pixg + i;
            outp[((size_t)(b * NHEADS + g) * NPIX + p) * HD + d] =
                (_Float16)((acc[i][j] + bb) * scale);
        }
    }
}

// ---------------- neighborhood attention, one thread per pixel-head ----------------
// grid: (8, 8, B*2), block 256 = 16x16 pixel tile
template<int K>
__global__ __launch_bounds__(256) void na2d_kernel(
    const _Float16* __restrict__ qh, const _Float16* __restrict__ kh,
    const _Float16* __restrict__ vh, const float* __restrict__ rpb,
    _Float16* __restrict__ ah, int head_base)
{
    constexpr int NS = K / 2;
    constexpr int RW = 2 * K - 1;
    int hi = blockIdx.z & 1;
    int b  = blockIdx.z >> 1;
    int g  = head_base + hi;
    int w = blockIdx.x * 16 + (threadIdx.x & 15);
    int h = blockIdx.y * 16 + (threadIdx.x >> 4);

    size_t plane = (size_t)(b * NHEADS + g) * NPIX;

    V64B qv;
    {
        const f4* qp = (const f4*)(qh + (plane + (size_t)h * WW + w) * HD);
        #pragma unroll
        for (int i = 0; i < 4; i++) qv.f[i] = qp[i];
    }

    int r0 = h - NS; r0 = r0 < 0 ? 0 : r0; if (r0 > HH - K) r0 = HH - K;
    int c0 = w - NS; c0 = c0 < 0 ? 0 : c0; if (c0 > WW - K) c0 = WW - K;

    const float* rpb_b = rpb + (size_t)hi * RW * RW
                       + (size_t)(r0 - h + K - 1) * RW + (c0 - w + K - 1);

    float acc[32] = {};
    float l = 0.f;

    #pragma unroll 1
    for (int ki = 0; ki < K; ki++) {
        const _Float16* krow = kh + (plane + (size_t)(r0 + ki) * WW + c0) * HD;
        const _Float16* vrow = vh + (plane + (size_t)(r0 + ki) * WW + c0) * HD;
        const float* rprow = rpb_b + ki * RW;
        for (int kj = 0; kj < K; kj++) {
            V64B kv;
            const f4* kp = (const f4*)(krow + kj * HD);
            #pragma unroll
            for (int i = 0; i < 4; i++) kv.f[i] = kp[i];
            float s = rprow[kj];
            #pragma unroll
            for (int i = 0; i < 16; i++)
                s = __builtin_amdgcn_fdot2(qv.h[i], kv.h[i], s, false);
            float p = __expf(s);
            l += p;
            V64B vv;
            const f4* vp = (const f4*)(vrow + kj * HD);
            #pragma unroll
            for (int i = 0; i < 4; i++) vv.f[i] = vp[i];
            #pragma unroll
            for (int i = 0; i < 16; i++) {
                acc[2 * i]     += p * (float)vv.h[i][0];
                acc[2 * i + 1] += p * (float)vv.h[i][1];
            }
        }
    }

    float inv = 1.f / l;
    V64B ov;
    #pragma unroll
    for (int i = 0; i < 16; i++) {
        h2 t2;
        t2[0] = (_Float16)(acc[2 * i] * inv);
        t2[1] = (_Float16)(acc[2 * i + 1] * inv);
        ov.h[i] = t2;
    }
    f4* op = (f4*)(ah + (plane + (size_t)h * WW + w) * HD);
    #pragma unroll
    for (int i = 0; i < 4; i++) op[i] = ov.f[i];
}

// ---------------- output projection: out[b,co,h,w] = attn[pixel,:] @ Wo + bo ----------------
__global__ __launch_bounds__(256) void oproj_kernel(
    const _Float16* __restrict__ ah, const float* __restrict__ Wo,
    const float* __restrict__ bo, float* __restrict__ outp)
{
    __shared__ float AsT[64][17];
    __shared__ float Ws[16][192];

    int t = threadIdx.x;
    int m0 = blockIdx.x * 64;
    int b  = m0 / NPIX;
    int p0 = m0 % NPIX;
    int pixg = (t & 15) * 4;
    int cog  = (t >> 4) * 12;

    float acc[4][12] = {};

    for (int k0 = 0; k0 < 192; k0 += 16) {
        int g = k0 >> 5, d0 = k0 & 31;
        const _Float16* abase = ah + ((size_t)(b * NHEADS + g) * NPIX + p0) * HD + d0;
        #pragma unroll
        for (int i = 0; i < 4; i++) {
            int e = t + i * 256;
            int ci = e & 15, pp = e >> 4;
            AsT[pp][ci] = (float)abase[(size_t)pp * HD + ci];
        }
        #pragma unroll
        for (int i = 0; i < 12; i++) {
            int e = t + i * 256;
            int ci = e / 192, co = e - ci * 192;
            Ws[ci][co] = Wo[(size_t)(k0 + ci) * 192 + co];
        }
        __syncthreads();
        #pragma unroll
        for (int kk = 0; kk < 16; kk++) {
            const f4* wrow = (const f4*)&Ws[kk][cog];
            f4 w0 = wrow[0], w1 = wrow[1], w2 = wrow[2];
            float a0 = AsT[pixg][kk], a1 = AsT[pixg + 1][kk];
            float a2 = AsT[pixg + 2][kk], a3 = AsT[pixg + 3][kk];
            float av[4] = {a0, a1, a2, a3};
            #pragma unroll
            for (int i = 0; i < 4; i++) {
                acc[i][0] += av[i] * w0[0]; acc[i][1] += av[i] * w0[1];
                acc[i][2] += av[i] * w0[2]; acc[i][3] += av[i] * w0[3];
                acc[i][4] += av[i] * w1[0]; acc[i][5] += av[i] * w1[1];
                acc[i][6] += av[i] * w1[2]; acc[i][7] += av[i] * w1[3];
                acc[i][8] += av[i] * w2[0]; acc[i][9] += av[i] * w2[1];
                acc[i][10] += av[i] * w2[2]; acc[i][11] += av[i] * w2[3];
            }
        }
        __syncthreads();
    }

    #pragma unroll
    for (int j = 0; j < 12; j++) {
        int co = cog + j;
        float bb = bo[co];
        float* obase = outp + ((size_t)b * 192 + co) * NPIX + p0 + pixg;
        #pragma unroll
        for (int i = 0; i < 4; i++) obase[i] = acc[i][j] + bb;
    }
}

extern "C" void kernel_launch(void* const* d_in, const int* in_sizes, int n_in,
                              void* d_out, int out_size, void* d_ws, size_t ws_size,
                              hipStream_t stream) {
    const float* x    = (const float*)d_in[0];
    const float* ctx  = (const float*)d_in[1];
    const float* Wq   = (const float*)d_in[2];
    const float* bq   = (const float*)d_in[3];
    const float* Wk   = (const float*)d_in[4];
    const float* bk   = (const float*)d_in[5];
    const float* Wv   = (const float*)d_in[6];
    const float* bv   = (const float*)d_in[7];
    const float* Wo   = (const float*)d_in[8];
    const float* bo   = (const float*)d_in[9];
    const float* rpb0 = (const float*)d_in[10];
    const float* rpb1 = (const float*)d_in[11];
    const float* rpb2 = (const float*)d_in[12];

    size_t N = (size_t)NB * NHEADS * NPIX * HD;   // 25,165,824 elements
    _Float16* qh = (_Float16*)d_ws;
    _Float16* kh = qh + N;
    _Float16* vh = kh + N;
    _Float16* ah = vh + N;
    float* outp = (float*)d_out;

    proj_kernel<<<dim3(2048, 1, 3), 256, 0, stream>>>(x, ctx, Wq, bq, Wk, bk, Wv, bv, qh, kh, vh);
    na2d_kernel<7><<<dim3(8, 8, NB * 2), 256, 0, stream>>>(qh, kh, vh, rpb0, ah, 0);
    na2d_kernel<9><<<dim3(8, 8, NB * 2), 256, 0, stream>>>(qh, kh, vh, rpb1, ah, 2);
    na2d_kernel<11><<<dim3(8, 8, NB * 2), 256, 0, stream>>>(qh, kh, vh, rpb2, ah, 4);
    oproj_kernel<<<2048, 256, 0, stream>>>(ah, Wo, bo, outp);
}

// Round 2
// 741.594 us; speedup vs baseline: 1.4298x; 1.4298x over previous
//
#include <hip/hip_runtime.h>
#include <hip/hip_fp16.h>

#define HH 128
#define WW 128
#define NPIX (HH*WW)
#define NB 8
#define NHEADS 6
#define HD 32
#define SCALE 0.17677669529663687f

typedef _Float16 h2 __attribute__((ext_vector_type(2)));
typedef _Float16 f16x4 __attribute__((ext_vector_type(4)));
typedef _Float16 f16x8 __attribute__((ext_vector_type(8)));
typedef float f4 __attribute__((ext_vector_type(4)));

union V64B { f4 f[4]; h2 h[16]; _Float16 s[32]; };

// ---------------- prep: WT[mat][n][k] fp16 from W[mat][k][n] fp32 ----------------
__global__ __launch_bounds__(256) void prep_wt(
    const float* __restrict__ Wq, const float* __restrict__ Wk,
    const float* __restrict__ Wv, _Float16* __restrict__ wt)
{
    int idx = blockIdx.x * 256 + threadIdx.x;      // 3*36864 total
    int mat = idx / 36864, rem = idx % 36864;
    int k = rem / 192, n = rem % 192;              // consecutive idx -> consecutive n: coalesced read
    const float* W = mat == 0 ? Wq : (mat == 1 ? Wk : Wv);
    wt[(size_t)mat * 36864 + (size_t)n * 192 + k] = (_Float16)W[(size_t)k * 192 + n];
}

// ---------------- MFMA projection: C[pix][192] = A[pix][192k] * W[192k][192] ----------------
// grid (1024, 1, 3): z=0 q(from x, scaled), z=1 k, z=2 v.  512 threads = 8 waves (2m x 4n).
// BM=128 pixels, BN=192 (full), BK=32 x 6 steps. Wave tile: 64m x 48n.
#define LDK 40   // padded fp16 k-stride (80B: 16B-aligned rows, ~2-way banks)
__global__ __launch_bounds__(512) void proj_mfma(
    const float* __restrict__ x, const float* __restrict__ ctx,
    const _Float16* __restrict__ wt,
    const float* __restrict__ bq, const float* __restrict__ bk, const float* __restrict__ bv,
    _Float16* __restrict__ qh, _Float16* __restrict__ kh, _Float16* __restrict__ vh)
{
    int z = blockIdx.z;
    const float* A = (z == 0) ? x : ctx;
    const _Float16* WT = wt + (size_t)z * 36864;
    const float* bias = (z == 0) ? bq : (z == 1 ? bk : bv);
    _Float16* outp = (z == 0) ? qh : (z == 1 ? kh : vh);
    float scale = (z == 0) ? SCALE : 1.f;

    __shared__ _Float16 As[128][LDK];
    __shared__ _Float16 Ws[192][LDK];

    int t = threadIdx.x;
    int m0 = blockIdx.x * 128;
    int b  = m0 / NPIX;
    int p0 = m0 % NPIX;
    const float* Ab = A + (size_t)b * 192 * NPIX + p0;

    int lane = t & 63;
    int wid  = t >> 6;
    int wm = wid & 1;        // 2 m-halves of 64
    int wn = wid >> 1;       // 4 n-quarters of 48
    int lr = lane & 15;
    int lk = lane >> 4;

    f4 acc[4][3] = {};

    for (int ks = 0; ks < 6; ks++) {
        int k0 = ks * 32;
        // stage A: 128 pix x 32 c (fp32 -> fp16 transpose into LDS). 4096 slots, 8/thread.
        #pragma unroll
        for (int i = 0; i < 8; i++) {
            int s = t + i * 512;
            int c = s >> 7, p = s & 127;
            As[p][c] = (_Float16)Ab[(size_t)(k0 + c) * NPIX + p];
        }
        // stage W: 192 n x 32 k fp16, b64 chunks. 1536 chunks, 3/thread.
        #pragma unroll
        for (int i = 0; i < 3; i++) {
            int c4 = t + i * 512;
            int n = c4 >> 3, k4 = (c4 & 7) * 4;
            *(f16x4*)&Ws[n][k4] = *(const f16x4*)&WT[(size_t)n * 192 + k0 + k4];
        }
        __syncthreads();

        f16x8 af[4], bf[3];
        #pragma unroll
        for (int mi = 0; mi < 4; mi++)
            af[mi] = *(const f16x8*)&As[wm * 64 + mi * 16 + lr][lk * 8];
        #pragma unroll
        for (int ni = 0; ni < 3; ni++)
            bf[ni] = *(const f16x8*)&Ws[wn * 48 + ni * 16 + lr][lk * 8];
        #pragma unroll
        for (int mi = 0; mi < 4; mi++)
            #pragma unroll
            for (int ni = 0; ni < 3; ni++)
                acc[mi][ni] = __builtin_amdgcn_mfma_f32_16x16x32_f16(af[mi], bf[ni], acc[mi][ni], 0, 0, 0);
        __syncthreads();
    }

    // epilogue: D[row=(lane>>4)*4+r][col=lane&15]
    #pragma unroll
    for (int ni = 0; ni < 3; ni++) {
        int n = wn * 48 + ni * 16 + lr;
        int g = n >> 5, d = n & 31;
        float bb = bias[n];
        _Float16* obase = outp + (size_t)(b * NHEADS + g) * NPIX * HD + d;
        #pragma unroll
        for (int mi = 0; mi < 4; mi++) {
            #pragma unroll
            for (int r = 0; r < 4; r++) {
                int p = p0 + wm * 64 + mi * 16 + lk * 4 + r;
                obase[(size_t)p * HD] = (_Float16)((acc[mi][ni][r] + bb) * scale);
            }
        }
    }
}

// ---------------- neighborhood attention, one thread per pixel-head ----------------
template<int K>
__global__ __launch_bounds__(256) void na2d_kernel(
    const _Float16* __restrict__ qh, const _Float16* __restrict__ kh,
    const _Float16* __restrict__ vh, const float* __restrict__ rpb,
    _Float16* __restrict__ ah, int head_base)
{
    constexpr int NS = K / 2;
    constexpr int RW = 2 * K - 1;
    int hi = blockIdx.z & 1;
    int b  = blockIdx.z >> 1;
    int g  = head_base + hi;
    int w = blockIdx.x * 16 + (threadIdx.x & 15);
    int h = blockIdx.y * 16 + (threadIdx.x >> 4);

    size_t plane = (size_t)(b * NHEADS + g) * NPIX;

    V64B qv;
    {
        const f4* qp = (const f4*)(qh + (plane + (size_t)h * WW + w) * HD);
        #pragma unroll
        for (int i = 0; i < 4; i++) qv.f[i] = qp[i];
    }

    int r0 = h - NS; r0 = r0 < 0 ? 0 : r0; if (r0 > HH - K) r0 = HH - K;
    int c0 = w - NS; c0 = c0 < 0 ? 0 : c0; if (c0 > WW - K) c0 = WW - K;

    const float* rpb_b = rpb + (size_t)hi * RW * RW
                       + (size_t)(r0 - h + K - 1) * RW + (c0 - w + K - 1);

    float acc[32] = {};
    float l = 0.f;

    #pragma unroll 1
    for (int ki = 0; ki < K; ki++) {
        const _Float16* krow = kh + (plane + (size_t)(r0 + ki) * WW + c0) * HD;
        const _Float16* vrow = vh + (plane + (size_t)(r0 + ki) * WW + c0) * HD;
        const float* rprow = rpb_b + ki * RW;
        for (int kj = 0; kj < K; kj++) {
            V64B kv;
            const f4* kp = (const f4*)(krow + kj * HD);
            #pragma unroll
            for (int i = 0; i < 4; i++) kv.f[i] = kp[i];
            float s = rprow[kj];
            #pragma unroll
            for (int i = 0; i < 16; i++)
                s = __builtin_amdgcn_fdot2(qv.h[i], kv.h[i], s, false);
            float p = __expf(s);
            l += p;
            V64B vv;
            const f4* vp = (const f4*)(vrow + kj * HD);
            #pragma unroll
            for (int i = 0; i < 4; i++) vv.f[i] = vp[i];
            #pragma unroll
            for (int i = 0; i < 16; i++) {
                acc[2 * i]     += p * (float)vv.h[i][0];
                acc[2 * i + 1] += p * (float)vv.h[i][1];
            }
        }
    }

    float inv = 1.f / l;
    V64B ov;
    #pragma unroll
    for (int i = 0; i < 16; i++) {
        h2 t2;
        t2[0] = (_Float16)(acc[2 * i] * inv);
        t2[1] = (_Float16)(acc[2 * i + 1] * inv);
        ov.h[i] = t2;
    }
    f4* op = (f4*)(ah + (plane + (size_t)h * WW + w) * HD);
    #pragma unroll
    for (int i = 0; i < 4; i++) op[i] = ov.f[i];
}

// ---------------- output projection ----------------
__global__ __launch_bounds__(256) void oproj_kernel(
    const _Float16* __restrict__ ah, const float* __restrict__ Wo,
    const float* __restrict__ bo, float* __restrict__ outp)
{
    __shared__ float AsT[64][17];
    __shared__ float Ws[16][192];

    int t = threadIdx.x;
    int m0 = blockIdx.x * 64;
    int b  = m0 / NPIX;
    int p0 = m0 % NPIX;
    int pixg = (t & 15) * 4;
    int cog  = (t >> 4) * 12;

    float acc[4][12] = {};

    for (int k0 = 0; k0 < 192; k0 += 16) {
        int g = k0 >> 5, d0 = k0 & 31;
        const _Float16* abase = ah + ((size_t)(b * NHEADS + g) * NPIX + p0) * HD + d0;
        #pragma unroll
        for (int i = 0; i < 4; i++) {
            int e = t + i * 256;
            int ci = e & 15, pp = e >> 4;
            AsT[pp][ci] = (float)abase[(size_t)pp * HD + ci];
        }
        #pragma unroll
        for (int i = 0; i < 12; i++) {
            int e = t + i * 256;
            int ci = e / 192, co = e - ci * 192;
            Ws[ci][co] = Wo[(size_t)(k0 + ci) * 192 + co];
        }
        __syncthreads();
        #pragma unroll
        for (int kk = 0; kk < 16; kk++) {
            const f4* wrow = (const f4*)&Ws[kk][cog];
            f4 w0 = wrow[0], w1 = wrow[1], w2 = wrow[2];
            float av[4] = {AsT[pixg][kk], AsT[pixg + 1][kk], AsT[pixg + 2][kk], AsT[pixg + 3][kk]};
            #pragma unroll
            for (int i = 0; i < 4; i++) {
                acc[i][0] += av[i] * w0[0]; acc[i][1] += av[i] * w0[1];
                acc[i][2] += av[i] * w0[2]; acc[i][3] += av[i] * w0[3];
                acc[i][4] += av[i] * w1[0]; acc[i][5] += av[i] * w1[1];
                acc[i][6] += av[i] * w1[2]; acc[i][7] += av[i] * w1[3];
                acc[i][8] += av[i] * w2[0]; acc[i][9] += av[i] * w2[1];
                acc[i][10] += av[i] * w2[2]; acc[i][11] += av[i] * w2[3];
            }
        }
        __syncthreads();
    }

    #pragma unroll
    for (int j = 0; j < 12; j++) {
        int co = cog + j;
        float bb = bo[co];
        float* obase = outp + ((size_t)b * 192 + co) * NPIX + p0 + pixg;
        #pragma unroll
        for (int i = 0; i < 4; i++) obase[i] = acc[i][j] + bb;
    }
}

extern "C" void kernel_launch(void* const* d_in, const int* in_sizes, int n_in,
                              void* d_out, int out_size, void* d_ws, size_t ws_size,
                              hipStream_t stream) {
    const float* x    = (const float*)d_in[0];
    const float* ctx  = (const float*)d_in[1];
    const float* Wq   = (const float*)d_in[2];
    const float* bq   = (const float*)d_in[3];
    const float* Wk   = (const float*)d_in[4];
    const float* bk   = (const float*)d_in[5];
    const float* Wv   = (const float*)d_in[6];
    const float* bv   = (const float*)d_in[7];
    const float* Wo   = (const float*)d_in[8];
    const float* bo   = (const float*)d_in[9];
    const float* rpb0 = (const float*)d_in[10];
    const float* rpb1 = (const float*)d_in[11];
    const float* rpb2 = (const float*)d_in[12];

    size_t N = (size_t)NB * NHEADS * NPIX * HD;   // 25,165,824 elements
    _Float16* qh = (_Float16*)d_ws;
    _Float16* kh = qh + N;
    _Float16* vh = kh + N;
    _Float16* ah = vh + N;
    _Float16* wt = ah;   // park WT fp16 (3*36864 elems) in ah region; na2d overwrites it later
    float* outp = (float*)d_out;

    prep_wt<<<432, 256, 0, stream>>>(Wq, Wk, Wv, wt);
    proj_mfma<<<dim3(1024, 1, 3), 512, 0, stream>>>(x, ctx, wt, bq, bk, bv, qh, kh, vh);
    na2d_kernel<7><<<dim3(8, 8, NB * 2), 256, 0, stream>>>(qh, kh, vh, rpb0, ah, 0);
    na2d_kernel<9><<<dim3(8, 8, NB * 2), 256, 0, stream>>>(qh, kh, vh, rpb1, ah, 2);
    na2d_kernel<11><<<dim3(8, 8, NB * 2), 256, 0, stream>>>(qh, kh, vh, rpb2, ah, 4);
    oproj_kernel<<<2048, 256, 0, stream>>>(ah, Wo, bo, outp);
}